// Round 18
// baseline (104.165 us; speedup 1.0000x reference)
//
#include <hip/hip_runtime.h>

// MultiModalFusion, analytic collapse + MOMENT-SERIES evaluation (no exp in hot loop):
//   out[b,n,i,s] = (Ebar/3) * sum_{j!=i} y_j(c_{i,s}) + bvbar,  c = alpha*x_i[s] + gamma
//   y_j(c) = N_j(c)/D_j(c);  with xhat = x_j/X_j (X_j = row absmax), z = c*X_j:
//     D_j(c) = sum_m z^m/m! * mu_m,   N_j(c) = X_j * sum_m z^m/m! * mu_{m+1},
//     mu_m = sum_t xhat_t^m   (98 moments per row, exp-free, built once per (b,n,j))
//   Series is entire; 98 terms converge to <1e-7 for |z|<=30 (|alpha| up to ~1.8 = 5sigma).
//   Forward recurrence P_m = P_{m-1}*z/m keeps all intermediates in fp32 range.
//
// Round-16 postmortem: occupancy 40/80/100% all flat, +VALU flat, dual-pipe flat ->
// the exp inner loop itself (160M v_exp + per-float4 LDS reads) is the cost. This
// version deletes it: main kernel is a pure-FMA stream over 1.2KB of wave-uniform
// (SGPR-cached) coefficients. No LDS, no syncthreads, no transcendentals.

#define XMAX_OFF 16
#define MU_OFF   1024

static __device__ __forceinline__ float hsum4(float4 v) { return (v.x + v.y) + (v.z + v.w); }

// One wave: alpha, gamma, Ebar, bvbar -> ws[0..3].  (unchanged, proven)
__global__ void mm_prep(const float* __restrict__ Wq, const float* __restrict__ bq,
                        const float* __restrict__ Wk, const float* __restrict__ bk,
                        const float* __restrict__ Wv, const float* __restrict__ bv,
                        float* __restrict__ ws) {
    const int k = threadIdx.x;  // 0..63
    const float4* wq4 = reinterpret_cast<const float4*>(Wq) + k * 32;
    const float4* wk4 = reinterpret_cast<const float4*>(Wk) + k * 32;
    const float4* wv4 = reinterpret_cast<const float4*>(Wv) + k * 32;
    float a = 0.f, c = 0.f, e = 0.f;
    #pragma unroll 8
    for (int d = 0; d < 32; ++d) {
        a += hsum4(wq4[d]);
        c += hsum4(wk4[d]);
        e += hsum4(wv4[d]);
    }
    float dac = a * c;
    float dcq = c * bq[k];
    float sbv = bv[k];
    #pragma unroll
    for (int off = 32; off > 0; off >>= 1) {
        dac += __shfl_down(dac, off, 64);
        dcq += __shfl_down(dcq, off, 64);
        e   += __shfl_down(e,   off, 64);
        sbv += __shfl_down(sbv, off, 64);
    }
    if (k == 0) {
        ws[0] = dac * 0.125f;          // alpha
        ws[1] = dcq * 0.125f;          // gamma
        ws[2] = e   * (1.0f / 64.0f);  // Ebar
        ws[3] = sbv * (1.0f / 64.0f);  // bvbar
    }
}

// 204 blocks x 256 thr; wave j builds the 98 moments of row (bn, j).
__global__ __launch_bounds__(256) void mm_moments(const float* __restrict__ x,
                                                  float* __restrict__ ws) {
    const int bn   = blockIdx.x;         // 0..203
    const int wid  = threadIdx.x >> 6;   // row j = 0..3
    const int lane = threadIdx.x & 63;
    const float4 v = reinterpret_cast<const float4*>(x + (size_t)bn * 1024 + wid * 256)[lane];
    // row absmax (butterfly)
    float a = fmaxf(fmaxf(fabsf(v.x), fabsf(v.y)), fmaxf(fabsf(v.z), fabsf(v.w)));
    #pragma unroll
    for (int k = 32; k > 0; k >>= 1) a = fmaxf(a, __shfl_xor(a, k, 64));
    const float inv = 1.0f / a;
    const float h0 = v.x * inv, h1 = v.y * inv, h2 = v.z * inv, h3 = v.w * inv;
    float p0 = 1.f, p1 = 1.f, p2 = 1.f, p3 = 1.f;
    float* mu = ws + MU_OFF + (size_t)(bn * 4 + wid) * 100;
    for (int m = 0; m < 98; ++m) {
        float s = (p0 + p1) + (p2 + p3);
        #pragma unroll
        for (int k = 32; k > 0; k >>= 1) s += __shfl_xor(s, k, 64);
        if (lane == 0) mu[m] = s;      // mu_0 = 256
        p0 *= h0; p1 *= h1; p2 *= h2; p3 *= h3;
    }
    if (lane == 0) {
        mu[98] = 0.f; mu[99] = 0.f;    // zero-pad for the float4 stream
        ws[XMAX_OFF + bn * 4 + wid] = a;
    }
}

// 816 blocks x 256 thr, thread = s. Pure-FMA series eval; no LDS, no sync.
__global__ __launch_bounds__(256) void mm_attn(const float* __restrict__ x,
                                               const float* __restrict__ ws,
                                               float* __restrict__ out) {
    const int bni = blockIdx.x;          // ((b*51+n)*4 + i)
    const int bn  = bni >> 2, i = bni & 3;
    const int tid = threadIdx.x;
    const float alpha = ws[0], gamma = ws[1], Ebar = ws[2], bvbar = ws[3];
    const float c = alpha * x[(size_t)bn * 1024 + i * 256 + tid] + gamma;

    float acc = 0.f;
    #pragma unroll
    for (int jj = 1; jj < 4; ++jj) {
        const int j = (i + jj) & 3;                       // uniform across block
        const float X = ws[XMAX_OFF + bn * 4 + j];
        const float4* mu4 = reinterpret_cast<const float4*>(ws + MU_OFF + (size_t)(bn * 4 + j) * 100);
        const float z = c * X;
        float4 cur = mu4[0];
        float P = 1.f, D = 0.f, N = 0.f;
        #pragma unroll
        for (int g = 0; g < 25; ++g) {                    // m = 4g .. 4g+3
            float4 nxt = (g < 24) ? mu4[g + 1] : make_float4(0.f, 0.f, 0.f, 0.f);
            D = fmaf(P, cur.x, D);  N = fmaf(P, cur.y, N);  P *= z * (1.0f / (4 * g + 1));
            D = fmaf(P, cur.y, D);  N = fmaf(P, cur.z, N);  P *= z * (1.0f / (4 * g + 2));
            D = fmaf(P, cur.z, D);  N = fmaf(P, cur.w, N);  P *= z * (1.0f / (4 * g + 3));
            D = fmaf(P, cur.w, D);  N = fmaf(P, nxt.x, N);  P *= z * (1.0f / (4 * g + 4));
            cur = nxt;
        }
        acc += X * N / D;
    }
    out[(size_t)bni * 256 + tid] = fmaf(Ebar * (1.0f / 3.0f), acc, bvbar);
}

extern "C" void kernel_launch(void* const* d_in, const int* in_sizes, int n_in,
                              void* d_out, int out_size, void* d_ws, size_t ws_size,
                              hipStream_t stream) {
    const float* x  = (const float*)d_in[0];
    const float* Wq = (const float*)d_in[1];
    const float* bq = (const float*)d_in[2];
    const float* Wk = (const float*)d_in[3];
    const float* bk = (const float*)d_in[4];
    const float* Wv = (const float*)d_in[5];
    const float* bv = (const float*)d_in[6];
    float* out = (float*)d_out;
    float* ws  = (float*)d_ws;   // [0:4) scalars, [16:832) xmax, [1024:82624) moments

    mm_prep<<<1, 64, 0, stream>>>(Wq, bq, Wk, bk, Wv, bv, ws);
    mm_moments<<<204, 256, 0, stream>>>(x, ws);
    mm_attn<<<816, 256, 0, stream>>>(x, ws, out);
}

// Round 19
// 96.322 us; speedup vs baseline: 1.0814x; 1.0814x over previous
//
#include <hip/hip_runtime.h>

// MultiModalFusion, analytic collapse + MOMENT-SERIES evaluation (no exp in hot loop):
//   out[b,n,i,s] = (Ebar/3) * sum_{j!=i} y_j(c_{i,s}) + bvbar,  c = alpha*x_i[s] + gamma
//   y_j(c) = N_j(c)/D_j(c);  with xhat = x_j/X_j (X_j = row absmax), z = c*X_j:
//     D_j(c) = sum_m z^m/m! * mu_m,   N_j(c) = X_j * sum_m z^m/m! * mu_{m+1},
//     mu_m = sum_t xhat_t^m   (98 moments per row, exp-free, built once per (b,n,j))
//   Proven R18: absmax 3.05e-5 (== exp version); series numerically sound.
//
// Round-18 postmortem: totals (R5 99.4, R16 98.1, R18 104.2) decoupled from kernel
// work (37 vs 10 us) -> window dominated by harness 268MB d_ws poison fill (~40us,
// 84% HBM peak) + restore/replay machinery. Only untested lever: graph node count.
// This round: 3 nodes -> 2 (prep merged as block 204 of the moments launch),
// moments+attn code byte-identical to proven R18.

#define XMAX_OFF 16
#define MU_OFF   1024

static __device__ __forceinline__ float hsum4(float4 v) { return (v.x + v.y) + (v.z + v.w); }

// Blocks 0..203: wave j builds the 98 moments of row (bn, j).
// Block 204: wave 0 computes alpha/gamma/Ebar/bvbar -> ws[0..3].
__global__ __launch_bounds__(256) void mm_build(const float* __restrict__ x,
                                                const float* __restrict__ Wq,
                                                const float* __restrict__ bq,
                                                const float* __restrict__ Wk,
                                                const float* __restrict__ bk,
                                                const float* __restrict__ Wv,
                                                const float* __restrict__ bv,
                                                float* __restrict__ ws) {
    if (blockIdx.x < 204) {
        const int bn   = blockIdx.x;         // 0..203
        const int wid  = threadIdx.x >> 6;   // row j = 0..3
        const int lane = threadIdx.x & 63;
        const float4 v = reinterpret_cast<const float4*>(x + (size_t)bn * 1024 + wid * 256)[lane];
        // row absmax (butterfly)
        float a = fmaxf(fmaxf(fabsf(v.x), fabsf(v.y)), fmaxf(fabsf(v.z), fabsf(v.w)));
        #pragma unroll
        for (int k = 32; k > 0; k >>= 1) a = fmaxf(a, __shfl_xor(a, k, 64));
        const float inv = 1.0f / a;
        const float h0 = v.x * inv, h1 = v.y * inv, h2 = v.z * inv, h3 = v.w * inv;
        float p0 = 1.f, p1 = 1.f, p2 = 1.f, p3 = 1.f;
        float* mu = ws + MU_OFF + (size_t)(bn * 4 + wid) * 100;
        for (int m = 0; m < 98; ++m) {
            float s = (p0 + p1) + (p2 + p3);
            #pragma unroll
            for (int k = 32; k > 0; k >>= 1) s += __shfl_xor(s, k, 64);
            if (lane == 0) mu[m] = s;      // mu_0 = 256
            p0 *= h0; p1 *= h1; p2 *= h2; p3 *= h3;
        }
        if (lane == 0) {
            mu[98] = 0.f; mu[99] = 0.f;    // zero-pad for the float4 stream
            ws[XMAX_OFF + bn * 4 + wid] = a;
        }
    } else if (threadIdx.x < 64) {
        const int k = threadIdx.x;  // 0..63
        const float4* wq4 = reinterpret_cast<const float4*>(Wq) + k * 32;
        const float4* wk4 = reinterpret_cast<const float4*>(Wk) + k * 32;
        const float4* wv4 = reinterpret_cast<const float4*>(Wv) + k * 32;
        float a = 0.f, c = 0.f, e = 0.f;
        #pragma unroll 8
        for (int d = 0; d < 32; ++d) {
            a += hsum4(wq4[d]);
            c += hsum4(wk4[d]);
            e += hsum4(wv4[d]);
        }
        float dac = a * c;
        float dcq = c * bq[k];
        float sbv = bv[k];
        #pragma unroll
        for (int off = 32; off > 0; off >>= 1) {
            dac += __shfl_down(dac, off, 64);
            dcq += __shfl_down(dcq, off, 64);
            e   += __shfl_down(e,   off, 64);
            sbv += __shfl_down(sbv, off, 64);
        }
        if (k == 0) {
            ws[0] = dac * 0.125f;          // alpha
            ws[1] = dcq * 0.125f;          // gamma
            ws[2] = e   * (1.0f / 64.0f);  // Ebar
            ws[3] = sbv * (1.0f / 64.0f);  // bvbar
        }
    }
}

// 816 blocks x 256 thr, thread = s. Pure-FMA series eval; no LDS, no sync.
__global__ __launch_bounds__(256) void mm_attn(const float* __restrict__ x,
                                               const float* __restrict__ ws,
                                               float* __restrict__ out) {
    const int bni = blockIdx.x;          // ((b*51+n)*4 + i)
    const int bn  = bni >> 2, i = bni & 3;
    const int tid = threadIdx.x;
    const float alpha = ws[0], gamma = ws[1], Ebar = ws[2], bvbar = ws[3];
    const float c = alpha * x[(size_t)bn * 1024 + i * 256 + tid] + gamma;

    float acc = 0.f;
    #pragma unroll
    for (int jj = 1; jj < 4; ++jj) {
        const int j = (i + jj) & 3;                       // uniform across block
        const float X = ws[XMAX_OFF + bn * 4 + j];
        const float4* mu4 = reinterpret_cast<const float4*>(ws + MU_OFF + (size_t)(bn * 4 + j) * 100);
        const float z = c * X;
        float4 cur = mu4[0];
        float P = 1.f, D = 0.f, N = 0.f;
        #pragma unroll
        for (int g = 0; g < 25; ++g) {                    // m = 4g .. 4g+3
            float4 nxt = (g < 24) ? mu4[g + 1] : make_float4(0.f, 0.f, 0.f, 0.f);
            D = fmaf(P, cur.x, D);  N = fmaf(P, cur.y, N);  P *= z * (1.0f / (4 * g + 1));
            D = fmaf(P, cur.y, D);  N = fmaf(P, cur.z, N);  P *= z * (1.0f / (4 * g + 2));
            D = fmaf(P, cur.z, D);  N = fmaf(P, cur.w, N);  P *= z * (1.0f / (4 * g + 3));
            D = fmaf(P, cur.w, D);  N = fmaf(P, nxt.x, N);  P *= z * (1.0f / (4 * g + 4));
            cur = nxt;
        }
        acc += X * N / D;
    }
    out[(size_t)bni * 256 + tid] = fmaf(Ebar * (1.0f / 3.0f), acc, bvbar);
}

extern "C" void kernel_launch(void* const* d_in, const int* in_sizes, int n_in,
                              void* d_out, int out_size, void* d_ws, size_t ws_size,
                              hipStream_t stream) {
    const float* x  = (const float*)d_in[0];
    const float* Wq = (const float*)d_in[1];
    const float* bq = (const float*)d_in[2];
    const float* Wk = (const float*)d_in[3];
    const float* bk = (const float*)d_in[4];
    const float* Wv = (const float*)d_in[5];
    const float* bv = (const float*)d_in[6];
    float* out = (float*)d_out;
    float* ws  = (float*)d_ws;   // [0:4) scalars, [16:832) xmax, [1024:82624) moments

    mm_build<<<205, 256, 0, stream>>>(x, Wq, bq, Wk, bk, Wv, bv, ws);
    mm_attn<<<816, 256, 0, stream>>>(x, ws, out);
}